// Round 5
// baseline (56705.029 us; speedup 1.0000x reference)
//
#include <hip/hip_runtime.h>
#include <cstdint>

// ---- problem constants ----
#define NT  4
#define NB  32
#define NC  512
#define NCH 2048
#define NN  196
#define NM  (NB * NN)   // 6272 columns = 98*64
#define NH  8

struct GP {
    const float *q_bn_s, *q_bn_b, *k_bn_s, *k_bn_b;
    const float *proj_b, *proj_bn_s, *proj_bn_b;
    const float *mlp1_b, *mlp1_bn_s, *mlp1_bn_b;
    const float *mlp2_b, *mlp2_bn_s, *mlp2_bn_b;
    const float *wqkT, *wprojT, *wmlp1T, *wmlp2T;  // [K][O] transposed weights
    const float *xT;                                // [T][C][M] permuted input
    float *xy;                                      // [C][M] x + y_spike (per t)
    float *v_q, *v_k, *v_y, *v_h1, *v_h2, *v_attn;  // LIF states, [C][M]
    unsigned char *q_sp, *k_sp, *h1_sp, *attn_sp;   // binary spikes
    float *out;
    int t;
};

// Exact-f32 LIF step (bitwise-validated vs reference in R2/R3/R4).
__device__ __forceinline__ float lif_step(float z, float v_old, float vth, int& sp) {
    float d = __fsub_rn(z, v_old);
    float h = __fmul_rn(d, 0.5f);
    float v = __fadd_rn(v_old, h);
    sp = (v >= vth) ? 1 : 0;
    return sp ? 0.0f : v;
}

typedef const void __attribute__((address_space(1))) gas_t;
typedef void __attribute__((address_space(3))) las_t;
__device__ __forceinline__ void gl_lds16(const float* g, float* l) {
    __builtin_amdgcn_global_load_lds((gas_t*)g, (las_t*)l, 16, 0, 0);
}

template <int N>
__device__ __forceinline__ void vmwait() {
    if constexpr (N == 0)      asm volatile("s_waitcnt vmcnt(0)" ::: "memory");
    else if constexpr (N == 2) asm volatile("s_waitcnt vmcnt(2)" ::: "memory");
    else if constexpr (N == 3) asm volatile("s_waitcnt vmcnt(3)" ::: "memory");
    else if constexpr (N == 4) asm volatile("s_waitcnt vmcnt(4)" ::: "memory");
    __builtin_amdgcn_sched_barrier(0);
}
__device__ __forceinline__ void lgkm0() {
    asm volatile("s_waitcnt lgkmcnt(0)" ::: "memory");
    __builtin_amdgcn_sched_barrier(0);
}
__device__ __forceinline__ void wgbar() {
    __builtin_amdgcn_s_barrier();
    __builtin_amdgcn_sched_barrier(0);
}

// ---------------- pre-kernels ----------------

// dst[c*ldD + offD + o] = src[o*K + c]   (32x32 LDS tiles)
__global__ __launch_bounds__(256) void trw_k(const float* __restrict__ src,
                                             float* __restrict__ dst,
                                             int K, int ldD, int offD) {
    __shared__ float tle[32][33];
    const int c0 = blockIdx.x * 32, o0 = blockIdx.y * 32;
    const int tx = threadIdx.x & 31, ty = threadIdx.x >> 5;
#pragma unroll
    for (int r = 0; r < 4; ++r)
        tle[ty + r * 8][tx] = src[(size_t)(o0 + ty + r * 8) * K + c0 + tx];
    __syncthreads();
#pragma unroll
    for (int r = 0; r < 4; ++r)
        dst[(size_t)(c0 + ty + r * 8) * ldD + offD + o0 + tx] = tle[tx][ty + r * 8];
}

// xT[t][c][b][n] = x[t][b][c][n]
__global__ __launch_bounds__(64) void permx_k(const float* __restrict__ x,
                                              float* __restrict__ xT) {
    const int id = blockIdx.x;         // t*16384 + c*32 + b
    const int b = id & 31;
    const int c = (id >> 5) & 511;
    const int t = id >> 14;
    const float* s = x + ((size_t)(t * NB + b) * NC + c) * NN;
    float* d = xT + ((size_t)(t * NC + c) * NB + b) * NN;
    for (int n = threadIdx.x; n < NN; n += 64) d[n] = s[n];
}

// attn LIF: per (h,m): integer sum of 64 q-spike bytes; LIF vth=0.5
__global__ __launch_bounds__(256) void attn_k(GP gp) {
    const int m = blockIdx.x * 256 + threadIdx.x;
    const int h = blockIdx.y;
    if (m >= NM) return;
    const unsigned char* q = gp.q_sp + (size_t)h * 64 * NM + m;
    int s = 0;
#pragma unroll 8
    for (int d = 0; d < 64; ++d) s += q[(size_t)d * NM];
    float v = gp.t ? gp.v_attn[(size_t)h * NM + m] : 0.0f;
    int sp;
    v = lif_step((float)s, v, 0.5f, sp);
    gp.v_attn[(size_t)h * NM + m] = v;
    gp.attn_sp[(size_t)h * NM + m] = (unsigned char)sp;
}

// ---------------- fused GEMM + BN + LIF ----------------
// 256 thr (4 waves), 64o x 64n tile, per-thread 4x4, BK=16.
// 4-buffer LDS ring, stage-ahead 3 (unfused) / 2 (fused),
// COUNTED vmcnt waits (never 0 mid-loop), raw s_barrier.
// MODE 0: q&k (O=1024,K=512), X=xT[t]                unfused mul+add
// MODE 1: proj (O=512,K=512), X=k_sp&attn_sp (u8)    fma (exact product)
// MODE 2: mlp1 (O=2048,K=512), X=xy                  unfused mul+add
// MODE 3: mlp2 (O=512,K=2048), X=h1_sp (u8)          fma; writes out
template <int MODE>
__global__ __launch_bounds__(256, 4) void gemm_lif(GP gp) {
    constexpr bool FUSED = (MODE == 1 || MODE == 3);
    constexpr int K_TOT = (MODE == 3) ? 2048 : 512;
    constexpr int LDA = (MODE == 0) ? 1024 : (MODE == 2) ? 2048 : 512;
    constexpr int BK = 16;
    constexpr int NIT = K_TOT / BK;   // 32 or 128, divisible by 4

    __shared__ float As[4][BK][64];   // 16 KB
    __shared__ float Xs[4][BK][64];   // 16 KB

    const int tid = threadIdx.x;
    const int lane = tid & 63;
    const int wid = tid >> 6;
    const int to = lane & 15;        // o-group: 4 rows each
    const int tn = lane >> 4;        // n-group within wave
    const int m0 = blockIdx.x * 64;
    const int o0 = blockIdx.y * 64;
    const int xoff = wid * 16 + tn * 4;
    const int mb = m0 + xoff;

    const float* wA = (MODE == 0) ? gp.wqkT : (MODE == 1) ? gp.wprojT
                    : (MODE == 2) ? gp.wmlp1T : gp.wmlp2T;
    const float* xf = (MODE == 0) ? gp.xT + (size_t)gp.t * NC * NM : gp.xy;

    const int arow = wid * 4 + (lane >> 4);   // staging row within BK-tile
    const int acol = (lane & 15) * 4;         // staging col (float)
    const int xrow = tid >> 4;                // 0..15 (byte staging)
    const int xcol = (tid & 15) * 4;          // 0..60

    auto stageA = [&](int b, int s) {
        gl_lds16(wA + (size_t)(s * BK + arow) * LDA + o0 + acol, &As[b][wid * 4][0]);
    };
    auto stageX = [&](int b, int s) {
        gl_lds16(xf + (size_t)(s * BK + arow) * NM + m0 + acol, &Xs[b][wid * 4][0]);
    };
    auto stageF = [&](int s, unsigned& k, unsigned& a) {
        const int c = s * BK + xrow;
        if constexpr (MODE == 1) {
            k = *(const unsigned*)(gp.k_sp + (size_t)c * NM + m0 + xcol);
            a = *(const unsigned*)(gp.attn_sp + (size_t)(c >> 6) * NM + m0 + xcol);
        } else {
            k = *(const unsigned*)(gp.h1_sp + (size_t)c * NM + m0 + xcol);
            (void)a;
        }
    };
    auto flush = [&](int b, unsigned k, unsigned a) {
        const unsigned w = (MODE == 1) ? (k & a) : k;   // {0,1} bytes: AND == product, exact
        float4 f;
        f.x = (float)(unsigned char)(w);
        f.y = (float)(unsigned char)(w >> 8);
        f.z = (float)(unsigned char)(w >> 16);
        f.w = (float)(w >> 24);
        *(float4*)&Xs[b][xrow][xcol] = f;
    };

    float acc[4][4];
#pragma unroll
    for (int i = 0; i < 4; ++i)
#pragma unroll
        for (int j = 0; j < 4; ++j) acc[i][j] = 0.0f;

    auto compute = [&](int cb) {
        const float* as = &As[cb][0][0];
        const float* xs = &Xs[cb][0][0];
        float4 af[2], xv[2];
        af[0] = *(const float4*)(as + to * 4);
        xv[0] = *(const float4*)(xs + xoff);
#pragma unroll
        for (int kk = 0; kk < BK; ++kk) {
            const int s = kk & 1;
            if (kk + 1 < BK) {
                af[s ^ 1] = *(const float4*)(as + (kk + 1) * 64 + to * 4);
                xv[s ^ 1] = *(const float4*)(xs + (kk + 1) * 64 + xoff);
            }
            const float a4[4] = {af[s].x, af[s].y, af[s].z, af[s].w};
            const float x4[4] = {xv[s].x, xv[s].y, xv[s].z, xv[s].w};
#pragma unroll
            for (int i = 0; i < 4; ++i)
#pragma unroll
                for (int j = 0; j < 4; ++j) {
                    if (FUSED) acc[i][j] = __fmaf_rn(a4[i], x4[j], acc[i][j]);
                    else       acc[i][j] = __fadd_rn(acc[i][j], __fmul_rn(a4[i], x4[j]));
                }
        }
    };

    unsigned xk0 = 0, xa0 = 0, xk1 = 0, xa1 = 0;   // fused byte-staging slots

    // ---- prologue ----
    if constexpr (!FUSED) {
        stageA(0, 0); stageX(0, 0);
        stageA(1, 1); stageX(1, 1);
        stageA(2, 2); stageX(2, 2);
        vmwait<4>();                  // step0 retired; steps 1,2 in flight
    } else {
        stageA(0, 0); stageF(0, xk0, xa0);
        stageA(1, 1); stageF(1, xk1, xa1);
        if constexpr (MODE == 1) vmwait<3>(); else vmwait<2>();
        flush(0, xk0, xa0);
        lgkm0();
    }
    wgbar();

    // body: one K-step. cb = LDS buffer (static per call site).
    auto body = [&](int i, int cb, unsigned& kC, unsigned& aC,
                    unsigned& kN, unsigned& aN) {
        if constexpr (!FUSED) {
            if (i + 3 < NIT) { stageA((cb + 3) & 3, i + 3); stageX((cb + 3) & 3, i + 3); }
        } else {
            if (i + 2 < NIT) { stageA((cb + 2) & 3, i + 2); stageF(i + 2, kC, aC); }
        }
        __builtin_amdgcn_sched_barrier(0);
        compute(cb);
        if (i + 1 < NIT) {
            const int rem = NIT - 1 - i;
            if constexpr (!FUSED) {
                if (rem >= 3) vmwait<4>();       // {i+1,i+2,i+3} in flight -> retire i+1
                else if (rem == 2) vmwait<2>();
                else vmwait<0>();
            } else if constexpr (MODE == 1) {
                if (rem >= 2) vmwait<3>(); else vmwait<0>();
            } else {
                if (rem >= 2) vmwait<2>(); else vmwait<0>();
            }
            if constexpr (FUSED) { flush((cb + 1) & 3, kN, aN); lgkm0(); }
            wgbar();
        }
    };

#pragma unroll 1
    for (int i = 0; i < NIT; i += 4) {
        body(i + 0, 0, xk0, xa0, xk1, xa1);
        body(i + 1, 1, xk1, xa1, xk0, xa0);
        body(i + 2, 2, xk0, xa0, xk1, xa1);
        body(i + 3, 3, xk1, xa1, xk0, xa0);
    }

    // ---- epilogue: BN + LIF, exact reference op order ----
    if constexpr (MODE == 0) {
        const bool isq = (o0 < NC);
        const float* bs = isq ? gp.q_bn_s : gp.k_bn_s;
        const float* bbv = isq ? gp.q_bn_b : gp.k_bn_b;
        float* vb = isq ? gp.v_q : gp.v_k;
        unsigned char* sb = isq ? gp.q_sp : gp.k_sp;
#pragma unroll
        for (int i = 0; i < 4; ++i) {
            const int oo = (o0 + to * 4 + i) & (NC - 1);
            const float sc = bs[oo], bc = bbv[oo];
            float* vr = vb + (size_t)oo * NM + mb;
            float4 vld = gp.t ? *(const float4*)vr : make_float4(0, 0, 0, 0);
            float vv[4] = {vld.x, vld.y, vld.z, vld.w};
            unsigned int pk = 0;
#pragma unroll
            for (int j = 0; j < 4; ++j) {
                const float z = __fadd_rn(__fmul_rn(acc[i][j], sc), bc);
                int sp;
                vv[j] = lif_step(z, vv[j], 1.0f, sp);
                pk |= (unsigned)sp << (j * 8);
            }
            *(float4*)vr = make_float4(vv[0], vv[1], vv[2], vv[3]);
            *(unsigned int*)(sb + (size_t)oo * NM + mb) = pk;
        }
    } else if constexpr (MODE == 2) {
#pragma unroll
        for (int i = 0; i < 4; ++i) {
            const int o = o0 + to * 4 + i;
            const float bi = gp.mlp1_b[o], sc = gp.mlp1_bn_s[o], bc = gp.mlp1_bn_b[o];
            float* vr = gp.v_h1 + (size_t)o * NM + mb;
            float4 vld = gp.t ? *(const float4*)vr : make_float4(0, 0, 0, 0);
            float vv[4] = {vld.x, vld.y, vld.z, vld.w};
            unsigned int pk = 0;
#pragma unroll
            for (int j = 0; j < 4; ++j) {
                const float z = __fadd_rn(__fmul_rn(__fadd_rn(acc[i][j], bi), sc), bc);
                int sp;
                vv[j] = lif_step(z, vv[j], 1.0f, sp);
                pk |= (unsigned)sp << (j * 8);
            }
            *(float4*)vr = make_float4(vv[0], vv[1], vv[2], vv[3]);
            *(unsigned int*)(gp.h1_sp + (size_t)o * NM + mb) = pk;
        }
    } else if constexpr (MODE == 1) {
#pragma unroll
        for (int i = 0; i < 4; ++i) {
            const int o = o0 + to * 4 + i;
            const float bi = gp.proj_b[o], sc = gp.proj_bn_s[o], bc = gp.proj_bn_b[o];
            float* vr = gp.v_y + (size_t)o * NM + mb;
            const float4 vld = gp.t ? *(const float4*)vr : make_float4(0, 0, 0, 0);
            const float4 xv4 = *(const float4*)(gp.xT + ((size_t)gp.t * NC + o) * NM + mb);
            float vv[4] = {vld.x, vld.y, vld.z, vld.w};
            const float xvv[4] = {xv4.x, xv4.y, xv4.z, xv4.w};
            float xyo[4];
#pragma unroll
            for (int j = 0; j < 4; ++j) {
                const float z = __fadd_rn(__fmul_rn(__fadd_rn(acc[i][j], bi), sc), bc);
                int sp;
                vv[j] = lif_step(z, vv[j], 1.0f, sp);
                xyo[j] = __fadd_rn(xvv[j], (float)sp);   // residual x + y (ref rounding)
            }
            *(float4*)vr = make_float4(vv[0], vv[1], vv[2], vv[3]);
            *(float4*)(gp.xy + (size_t)o * NM + mb) = make_float4(xyo[0], xyo[1], xyo[2], xyo[3]);
        }
    } else {  // MODE 3
#pragma unroll
        for (int i = 0; i < 4; ++i) {
            const int o = o0 + to * 4 + i;
            const float bi = gp.mlp2_b[o], sc = gp.mlp2_bn_s[o], bc = gp.mlp2_bn_b[o];
            float* vr = gp.v_h2 + (size_t)o * NM + mb;
            const float4 vld = gp.t ? *(const float4*)vr : make_float4(0, 0, 0, 0);
            const float4 xyv = *(const float4*)(gp.xy + (size_t)o * NM + mb);
            float vv[4] = {vld.x, vld.y, vld.z, vld.w};
            const float xyf[4] = {xyv.x, xyv.y, xyv.z, xyv.w};
            float4 og;
            float ov[4];
#pragma unroll
            for (int j = 0; j < 4; ++j) {
                const float z = __fadd_rn(__fmul_rn(__fadd_rn(acc[i][j], bi), sc), bc);
                int sp;
                vv[j] = lif_step(z, vv[j], 1.0f, sp);
                ov[j] = __fadd_rn(xyf[j], (float)sp);
            }
            og = make_float4(ov[0], ov[1], ov[2], ov[3]);
            const int b = mb / NN;               // mb, NN both multiples of 4
            const int n = mb - b * NN;
            *(float4*)&gp.out[(((size_t)gp.t * NB + b) * NC + o) * NN + n] = og;
            *(float4*)vr = make_float4(vv[0], vv[1], vv[2], vv[3]);
        }
    }
}

extern "C" void kernel_launch(void* const* d_in, const int* in_sizes, int n_in,
                              void* d_out, int out_size, void* d_ws, size_t ws_size,
                              hipStream_t stream) {
    const float* x       = (const float*)d_in[0];
    const float* q_w     = (const float*)d_in[1];
    const float* k_w     = (const float*)d_in[4];
    const float* proj_w  = (const float*)d_in[7];
    const float* mlp1_w  = (const float*)d_in[11];
    const float* mlp2_w  = (const float*)d_in[15];

    GP gp;
    gp.q_bn_s = (const float*)d_in[2];  gp.q_bn_b = (const float*)d_in[3];
    gp.k_bn_s = (const float*)d_in[5];  gp.k_bn_b = (const float*)d_in[6];
    gp.proj_b = (const float*)d_in[8];  gp.proj_bn_s = (const float*)d_in[9];  gp.proj_bn_b = (const float*)d_in[10];
    gp.mlp1_b = (const float*)d_in[12]; gp.mlp1_bn_s = (const float*)d_in[13]; gp.mlp1_bn_b = (const float*)d_in[14];
    gp.mlp2_b = (const float*)d_in[16]; gp.mlp2_bn_s = (const float*)d_in[17]; gp.mlp2_bn_b = (const float*)d_in[18];
    gp.out = (float*)d_out;

    char* ws = (char*)d_ws;
    size_t off = 0;
    auto alloc = [&](size_t bytes) -> void* {
        void* r = ws + off;
        off += (bytes + 255) & ~(size_t)255;
        return r;
    };
    float* wqkT   = (float*)alloc((size_t)512 * 1024 * 4);
    float* wprojT = (float*)alloc((size_t)512 * 512 * 4);
    float* wmlp1T = (float*)alloc((size_t)512 * 2048 * 4);
    float* wmlp2T = (float*)alloc((size_t)2048 * 512 * 4);
    float* xT     = (float*)alloc((size_t)NT * NC * NM * 4);
    gp.xy     = (float*)alloc((size_t)NC * NM * 4);
    gp.v_q    = (float*)alloc((size_t)NC * NM * 4);
    gp.v_k    = (float*)alloc((size_t)NC * NM * 4);
    gp.v_y    = (float*)alloc((size_t)NC * NM * 4);
    gp.v_h2   = (float*)alloc((size_t)NC * NM * 4);
    gp.v_h1   = (float*)alloc((size_t)NCH * NM * 4);
    gp.v_attn = (float*)alloc((size_t)NH * NM * 4);
    gp.q_sp   = (unsigned char*)alloc((size_t)NC * NM);
    gp.k_sp   = (unsigned char*)alloc((size_t)NC * NM);
    gp.h1_sp  = (unsigned char*)alloc((size_t)NCH * NM);
    gp.attn_sp= (unsigned char*)alloc((size_t)NH * NM);
    gp.wqkT = wqkT; gp.wprojT = wprojT; gp.wmlp1T = wmlp1T; gp.wmlp2T = wmlp2T;
    gp.xT = xT;

    // one-time (per call) layout transforms
    trw_k<<<dim3(16, 16), 256, 0, stream>>>(q_w,    wqkT,   512,  1024, 0);
    trw_k<<<dim3(16, 16), 256, 0, stream>>>(k_w,    wqkT,   512,  1024, 512);
    trw_k<<<dim3(16, 16), 256, 0, stream>>>(proj_w, wprojT, 512,  512,  0);
    trw_k<<<dim3(16, 64), 256, 0, stream>>>(mlp1_w, wmlp1T, 512,  2048, 0);
    trw_k<<<dim3(64, 16), 256, 0, stream>>>(mlp2_w, wmlp2T, 2048, 512,  0);
    permx_k<<<NT * NC * NB, 64, 0, stream>>>(x, xT);

    for (int t = 0; t < NT; ++t) {
        gp.t = t;
        gemm_lif<0><<<dim3(98, 16), 256, 0, stream>>>(gp);  // q,k
        attn_k<<<dim3(25, NH), 256, 0, stream>>>(gp);       // attn LIF
        gemm_lif<1><<<dim3(98, 8), 256, 0, stream>>>(gp);   // proj -> v_y, xy
        gemm_lif<2><<<dim3(98, 32), 256, 0, stream>>>(gp);  // mlp1 -> h1_sp
        gemm_lif<3><<<dim3(98, 8), 256, 0, stream>>>(gp);   // mlp2 -> out
    }
}

// Round 6
// 7853.683 us; speedup vs baseline: 7.2202x; 7.2202x over previous
//
#include <hip/hip_runtime.h>
#include <cstdint>

// ---- problem constants ----
#define NT  4
#define NB  32
#define NC  512
#define NCH 2048
#define NN  196
#define NM  (NB * NN)   // 6272 columns = 98*64
#define NH  8

struct GP {
    const float *q_bn_s, *q_bn_b, *k_bn_s, *k_bn_b;
    const float *proj_b, *proj_bn_s, *proj_bn_b;
    const float *mlp1_b, *mlp1_bn_s, *mlp1_bn_b;
    const float *mlp2_b, *mlp2_bn_s, *mlp2_bn_b;
    const float *wqkT, *wprojT, *wmlp1T, *wmlp2T;  // [K][O] transposed weights
    const float *xT;                                // [T][C][M] permuted input
    float *xy;                                      // [C][M] x + y_spike (per t)
    float *v_q, *v_k, *v_y, *v_h1, *v_h2, *v_attn;  // LIF states, [C][M]
    unsigned char *q_sp, *k_sp, *h1_sp, *attn_sp;   // binary spikes
    float *out;
    int t;
};

// Exact-f32 LIF step (bitwise-validated vs reference in R2-R5).
__device__ __forceinline__ float lif_step(float z, float v_old, float vth, int& sp) {
    float d = __fsub_rn(z, v_old);
    float h = __fmul_rn(d, 0.5f);
    float v = __fadd_rn(v_old, h);
    sp = (v >= vth) ? 1 : 0;
    return sp ? 0.0f : v;
}

typedef const void __attribute__((address_space(1))) gas_t;
typedef void __attribute__((address_space(3))) las_t;
__device__ __forceinline__ void gl_lds16(const float* g, float* l) {
    __builtin_amdgcn_global_load_lds((gas_t*)g, (las_t*)l, 16, 0, 0);
}

template <int N>
__device__ __forceinline__ void vmwait() {
    if constexpr (N == 0)      asm volatile("s_waitcnt vmcnt(0)" ::: "memory");
    else if constexpr (N == 2) asm volatile("s_waitcnt vmcnt(2)" ::: "memory");
    else if constexpr (N == 3) asm volatile("s_waitcnt vmcnt(3)" ::: "memory");
    else if constexpr (N == 4) asm volatile("s_waitcnt vmcnt(4)" ::: "memory");
    __builtin_amdgcn_sched_barrier(0);
}
__device__ __forceinline__ void lgkm0() {
    asm volatile("s_waitcnt lgkmcnt(0)" ::: "memory");
    __builtin_amdgcn_sched_barrier(0);
}
__device__ __forceinline__ void wgbar() {
    __builtin_amdgcn_s_barrier();
    __builtin_amdgcn_sched_barrier(0);
}

// ---------------- pre-kernels ----------------

// dst[c*ldD + offD + o] = src[o*K + c]   (32x32 LDS tiles)
__global__ __launch_bounds__(256) void trw_k(const float* __restrict__ src,
                                             float* __restrict__ dst,
                                             int K, int ldD, int offD) {
    __shared__ float tle[32][33];
    const int c0 = blockIdx.x * 32, o0 = blockIdx.y * 32;
    const int tx = threadIdx.x & 31, ty = threadIdx.x >> 5;
#pragma unroll
    for (int r = 0; r < 4; ++r)
        tle[ty + r * 8][tx] = src[(size_t)(o0 + ty + r * 8) * K + c0 + tx];
    __syncthreads();
#pragma unroll
    for (int r = 0; r < 4; ++r)
        dst[(size_t)(c0 + ty + r * 8) * ldD + offD + o0 + tx] = tle[tx][ty + r * 8];
}

// xT[t][c][b][n] = x[t][b][c][n]
__global__ __launch_bounds__(64) void permx_k(const float* __restrict__ x,
                                              float* __restrict__ xT) {
    const int id = blockIdx.x;         // t*16384 + c*32 + b
    const int b = id & 31;
    const int c = (id >> 5) & 511;
    const int t = id >> 14;
    const float* s = x + ((size_t)(t * NB + b) * NC + c) * NN;
    float* d = xT + ((size_t)(t * NC + c) * NB + b) * NN;
    for (int n = threadIdx.x; n < NN; n += 64) d[n] = s[n];
}

// attn LIF: per (h,m): integer sum of 64 q-spike bytes; LIF vth=0.5
__global__ __launch_bounds__(256) void attn_k(GP gp) {
    const int m = blockIdx.x * 256 + threadIdx.x;
    const int h = blockIdx.y;
    if (m >= NM) return;
    const unsigned char* q = gp.q_sp + (size_t)h * 64 * NM + m;
    int s = 0;
#pragma unroll 8
    for (int d = 0; d < 64; ++d) s += q[(size_t)d * NM];
    float v = gp.t ? gp.v_attn[(size_t)h * NM + m] : 0.0f;
    int sp;
    v = lif_step((float)s, v, 0.5f, sp);
    gp.v_attn[(size_t)h * NM + m] = v;
    gp.attn_sp[(size_t)h * NM + m] = (unsigned char)sp;
}

// ---------------- fused GEMM + BN + LIF ----------------
// 256 thr (4 waves), 64o x 64n tile, per-thread 4x4, BK=16.
// 4-buffer LDS ring, stage-ahead 3 (unfused) / 2 (fused),
// COUNTED vmcnt waits (never 0 mid-loop), raw s_barrier.
// NO second launch_bounds arg: R5's ",4" forced VGPR=64 -> scratch spill
// catastrophe (WRITE_SIZE 10 GB/dispatch, VALUBusy 2%). Let RA pick.
// MODE 0: q&k (O=1024,K=512), X=xT[t]                unfused mul+add
// MODE 1: proj (O=512,K=512), X=k_sp&attn_sp (u8)    fma (exact product)
// MODE 2: mlp1 (O=2048,K=512), X=xy                  unfused mul+add
// MODE 3: mlp2 (O=512,K=2048), X=h1_sp (u8)          fma; writes out
template <int MODE>
__global__ __launch_bounds__(256) void gemm_lif(GP gp) {
    constexpr bool FUSED = (MODE == 1 || MODE == 3);
    constexpr int K_TOT = (MODE == 3) ? 2048 : 512;
    constexpr int LDA = (MODE == 0) ? 1024 : (MODE == 2) ? 2048 : 512;
    constexpr int BK = 16;
    constexpr int NIT = K_TOT / BK;   // 32 or 128, divisible by 4

    __shared__ float As[4][BK][64];   // 16 KB
    __shared__ float Xs[4][BK][64];   // 16 KB

    const int tid = threadIdx.x;
    const int lane = tid & 63;
    const int wid = tid >> 6;
    const int to = lane & 15;        // o-group: 4 rows each
    const int tn = lane >> 4;        // n-group within wave
    const int m0 = blockIdx.x * 64;
    const int o0 = blockIdx.y * 64;
    const int xoff = wid * 16 + tn * 4;
    const int mb = m0 + xoff;

    const float* wA = (MODE == 0) ? gp.wqkT : (MODE == 1) ? gp.wprojT
                    : (MODE == 2) ? gp.wmlp1T : gp.wmlp2T;
    const float* xf = (MODE == 0) ? gp.xT + (size_t)gp.t * NC * NM : gp.xy;

    const int arow = wid * 4 + (lane >> 4);   // staging row within BK-tile
    const int acol = (lane & 15) * 4;         // staging col (float)
    const int xrow = tid >> 4;                // 0..15 (byte staging)
    const int xcol = (tid & 15) * 4;          // 0..60

    auto stageA = [&](int b, int s) {
        gl_lds16(wA + (size_t)(s * BK + arow) * LDA + o0 + acol, &As[b][wid * 4][0]);
    };
    auto stageX = [&](int b, int s) {
        gl_lds16(xf + (size_t)(s * BK + arow) * NM + m0 + acol, &Xs[b][wid * 4][0]);
    };
    auto stageF = [&](int s, unsigned& k, unsigned& a) {
        const int c = s * BK + xrow;
        if constexpr (MODE == 1) {
            k = *(const unsigned*)(gp.k_sp + (size_t)c * NM + m0 + xcol);
            a = *(const unsigned*)(gp.attn_sp + (size_t)(c >> 6) * NM + m0 + xcol);
        } else {
            k = *(const unsigned*)(gp.h1_sp + (size_t)c * NM + m0 + xcol);
            (void)a;
        }
    };
    auto flush = [&](int b, unsigned k, unsigned a) {
        const unsigned w = (MODE == 1) ? (k & a) : k;   // {0,1} bytes: AND == product, exact
        float4 f;
        f.x = (float)(unsigned char)(w);
        f.y = (float)(unsigned char)(w >> 8);
        f.z = (float)(unsigned char)(w >> 16);
        f.w = (float)(w >> 24);
        *(float4*)&Xs[b][xrow][xcol] = f;
    };

    float acc[4][4];
#pragma unroll
    for (int i = 0; i < 4; ++i)
#pragma unroll
        for (int j = 0; j < 4; ++j) acc[i][j] = 0.0f;

    auto compute = [&](int cb) {
        const float* as = &As[cb][0][0];
        const float* xs = &Xs[cb][0][0];
#pragma unroll
        for (int kk = 0; kk < BK; ++kk) {
            const float4 av = *(const float4*)(as + kk * 64 + to * 4);
            const float4 xv = *(const float4*)(xs + kk * 64 + xoff);
            const float a4[4] = {av.x, av.y, av.z, av.w};
            const float x4[4] = {xv.x, xv.y, xv.z, xv.w};
#pragma unroll
            for (int i = 0; i < 4; ++i)
#pragma unroll
                for (int j = 0; j < 4; ++j) {
                    if (FUSED) acc[i][j] = __fmaf_rn(a4[i], x4[j], acc[i][j]);
                    else       acc[i][j] = __fadd_rn(acc[i][j], __fmul_rn(a4[i], x4[j]));
                }
        }
    };

    unsigned xk0 = 0, xa0 = 0, xk1 = 0, xa1 = 0;   // fused byte-staging slots

    // ---- prologue ----
    if constexpr (!FUSED) {
        stageA(0, 0); stageX(0, 0);
        stageA(1, 1); stageX(1, 1);
        stageA(2, 2); stageX(2, 2);
        vmwait<4>();                  // step0 retired; steps 1,2 in flight
    } else {
        stageA(0, 0); stageF(0, xk0, xa0);
        stageA(1, 1); stageF(1, xk1, xa1);
        if constexpr (MODE == 1) vmwait<3>(); else vmwait<2>();
        flush(0, xk0, xa0);
        lgkm0();
    }
    wgbar();

    // body: one K-step. cb = LDS buffer (static per call site).
    auto body = [&](int i, int cb, unsigned& kC, unsigned& aC,
                    unsigned& kN, unsigned& aN) {
        if constexpr (!FUSED) {
            if (i + 3 < NIT) { stageA((cb + 3) & 3, i + 3); stageX((cb + 3) & 3, i + 3); }
        } else {
            if (i + 2 < NIT) { stageA((cb + 2) & 3, i + 2); stageF(i + 2, kC, aC); }
        }
        __builtin_amdgcn_sched_barrier(0);
        compute(cb);
        if (i + 1 < NIT) {
            const int rem = NIT - 1 - i;
            if constexpr (!FUSED) {
                if (rem >= 3) vmwait<4>();       // {i+1,i+2,i+3} in flight -> retire i+1
                else if (rem == 2) vmwait<2>();
                else vmwait<0>();
            } else if constexpr (MODE == 1) {
                if (rem >= 2) vmwait<3>(); else vmwait<0>();
            } else {
                if (rem >= 2) vmwait<2>(); else vmwait<0>();
            }
            if constexpr (FUSED) { flush((cb + 1) & 3, kN, aN); lgkm0(); }
            wgbar();
        }
    };

#pragma unroll 1
    for (int i = 0; i < NIT; i += 4) {
        body(i + 0, 0, xk0, xa0, xk1, xa1);
        body(i + 1, 1, xk1, xa1, xk0, xa0);
        body(i + 2, 2, xk0, xa0, xk1, xa1);
        body(i + 3, 3, xk1, xa1, xk0, xa0);
    }

    // ---- epilogue: BN + LIF, exact reference op order ----
    if constexpr (MODE == 0) {
        const bool isq = (o0 < NC);
        const float* bs = isq ? gp.q_bn_s : gp.k_bn_s;
        const float* bbv = isq ? gp.q_bn_b : gp.k_bn_b;
        float* vb = isq ? gp.v_q : gp.v_k;
        unsigned char* sb = isq ? gp.q_sp : gp.k_sp;
#pragma unroll
        for (int i = 0; i < 4; ++i) {
            const int oo = (o0 + to * 4 + i) & (NC - 1);
            const float sc = bs[oo], bc = bbv[oo];
            float* vr = vb + (size_t)oo * NM + mb;
            float4 vld = gp.t ? *(const float4*)vr : make_float4(0, 0, 0, 0);
            float vv[4] = {vld.x, vld.y, vld.z, vld.w};
            unsigned int pk = 0;
#pragma unroll
            for (int j = 0; j < 4; ++j) {
                const float z = __fadd_rn(__fmul_rn(acc[i][j], sc), bc);
                int sp;
                vv[j] = lif_step(z, vv[j], 1.0f, sp);
                pk |= (unsigned)sp << (j * 8);
            }
            *(float4*)vr = make_float4(vv[0], vv[1], vv[2], vv[3]);
            *(unsigned int*)(sb + (size_t)oo * NM + mb) = pk;
        }
    } else if constexpr (MODE == 2) {
#pragma unroll
        for (int i = 0; i < 4; ++i) {
            const int o = o0 + to * 4 + i;
            const float bi = gp.mlp1_b[o], sc = gp.mlp1_bn_s[o], bc = gp.mlp1_bn_b[o];
            float* vr = gp.v_h1 + (size_t)o * NM + mb;
            float4 vld = gp.t ? *(const float4*)vr : make_float4(0, 0, 0, 0);
            float vv[4] = {vld.x, vld.y, vld.z, vld.w};
            unsigned int pk = 0;
#pragma unroll
            for (int j = 0; j < 4; ++j) {
                const float z = __fadd_rn(__fmul_rn(__fadd_rn(acc[i][j], bi), sc), bc);
                int sp;
                vv[j] = lif_step(z, vv[j], 1.0f, sp);
                pk |= (unsigned)sp << (j * 8);
            }
            *(float4*)vr = make_float4(vv[0], vv[1], vv[2], vv[3]);
            *(unsigned int*)(gp.h1_sp + (size_t)o * NM + mb) = pk;
        }
    } else if constexpr (MODE == 1) {
#pragma unroll
        for (int i = 0; i < 4; ++i) {
            const int o = o0 + to * 4 + i;
            const float bi = gp.proj_b[o], sc = gp.proj_bn_s[o], bc = gp.proj_bn_b[o];
            float* vr = gp.v_y + (size_t)o * NM + mb;
            const float4 vld = gp.t ? *(const float4*)vr : make_float4(0, 0, 0, 0);
            const float4 xv4 = *(const float4*)(gp.xT + ((size_t)gp.t * NC + o) * NM + mb);
            float vv[4] = {vld.x, vld.y, vld.z, vld.w};
            const float xvv[4] = {xv4.x, xv4.y, xv4.z, xv4.w};
            float xyo[4];
#pragma unroll
            for (int j = 0; j < 4; ++j) {
                const float z = __fadd_rn(__fmul_rn(__fadd_rn(acc[i][j], bi), sc), bc);
                int sp;
                vv[j] = lif_step(z, vv[j], 1.0f, sp);
                xyo[j] = __fadd_rn(xvv[j], (float)sp);   // residual x + y (ref rounding)
            }
            *(float4*)vr = make_float4(vv[0], vv[1], vv[2], vv[3]);
            *(float4*)(gp.xy + (size_t)o * NM + mb) = make_float4(xyo[0], xyo[1], xyo[2], xyo[3]);
        }
    } else {  // MODE 3
#pragma unroll
        for (int i = 0; i < 4; ++i) {
            const int o = o0 + to * 4 + i;
            const float bi = gp.mlp2_b[o], sc = gp.mlp2_bn_s[o], bc = gp.mlp2_bn_b[o];
            float* vr = gp.v_h2 + (size_t)o * NM + mb;
            const float4 vld = gp.t ? *(const float4*)vr : make_float4(0, 0, 0, 0);
            const float4 xyv = *(const float4*)(gp.xy + (size_t)o * NM + mb);
            float vv[4] = {vld.x, vld.y, vld.z, vld.w};
            const float xyf[4] = {xyv.x, xyv.y, xyv.z, xyv.w};
            float ov[4];
#pragma unroll
            for (int j = 0; j < 4; ++j) {
                const float z = __fadd_rn(__fmul_rn(__fadd_rn(acc[i][j], bi), sc), bc);
                int sp;
                vv[j] = lif_step(z, vv[j], 1.0f, sp);
                ov[j] = __fadd_rn(xyf[j], (float)sp);
            }
            const int b = mb / NN;               // mb, NN both multiples of 4
            const int n = mb - b * NN;
            *(float4*)&gp.out[(((size_t)gp.t * NB + b) * NC + o) * NN + n] =
                make_float4(ov[0], ov[1], ov[2], ov[3]);
            *(float4*)vr = make_float4(vv[0], vv[1], vv[2], vv[3]);
        }
    }
}

extern "C" void kernel_launch(void* const* d_in, const int* in_sizes, int n_in,
                              void* d_out, int out_size, void* d_ws, size_t ws_size,
                              hipStream_t stream) {
    const float* x       = (const float*)d_in[0];
    const float* q_w     = (const float*)d_in[1];
    const float* k_w     = (const float*)d_in[4];
    const float* proj_w  = (const float*)d_in[7];
    const float* mlp1_w  = (const float*)d_in[11];
    const float* mlp2_w  = (const float*)d_in[15];

    GP gp;
    gp.q_bn_s = (const float*)d_in[2];  gp.q_bn_b = (const float*)d_in[3];
    gp.k_bn_s = (const float*)d_in[5];  gp.k_bn_b = (const float*)d_in[6];
    gp.proj_b = (const float*)d_in[8];  gp.proj_bn_s = (const float*)d_in[9];  gp.proj_bn_b = (const float*)d_in[10];
    gp.mlp1_b = (const float*)d_in[12]; gp.mlp1_bn_s = (const float*)d_in[13]; gp.mlp1_bn_b = (const float*)d_in[14];
    gp.mlp2_b = (const float*)d_in[16]; gp.mlp2_bn_s = (const float*)d_in[17]; gp.mlp2_bn_b = (const float*)d_in[18];
    gp.out = (float*)d_out;

    char* ws = (char*)d_ws;
    size_t off = 0;
    auto alloc = [&](size_t bytes) -> void* {
        void* r = ws + off;
        off += (bytes + 255) & ~(size_t)255;
        return r;
    };
    float* wqkT   = (float*)alloc((size_t)512 * 1024 * 4);
    float* wprojT = (float*)alloc((size_t)512 * 512 * 4);
    float* wmlp1T = (float*)alloc((size_t)512 * 2048 * 4);
    float* wmlp2T = (float*)alloc((size_t)2048 * 512 * 4);
    float* xT     = (float*)alloc((size_t)NT * NC * NM * 4);
    gp.xy     = (float*)alloc((size_t)NC * NM * 4);
    gp.v_q    = (float*)alloc((size_t)NC * NM * 4);
    gp.v_k    = (float*)alloc((size_t)NC * NM * 4);
    gp.v_y    = (float*)alloc((size_t)NC * NM * 4);
    gp.v_h2   = (float*)alloc((size_t)NC * NM * 4);
    gp.v_h1   = (float*)alloc((size_t)NCH * NM * 4);
    gp.v_attn = (float*)alloc((size_t)NH * NM * 4);
    gp.q_sp   = (unsigned char*)alloc((size_t)NC * NM);
    gp.k_sp   = (unsigned char*)alloc((size_t)NC * NM);
    gp.h1_sp  = (unsigned char*)alloc((size_t)NCH * NM);
    gp.attn_sp= (unsigned char*)alloc((size_t)NH * NM);
    gp.wqkT = wqkT; gp.wprojT = wprojT; gp.wmlp1T = wmlp1T; gp.wmlp2T = wmlp2T;
    gp.xT = xT;

    // one-time (per call) layout transforms
    trw_k<<<dim3(16, 16), 256, 0, stream>>>(q_w,    wqkT,   512,  1024, 0);
    trw_k<<<dim3(16, 16), 256, 0, stream>>>(k_w,    wqkT,   512,  1024, 512);
    trw_k<<<dim3(16, 16), 256, 0, stream>>>(proj_w, wprojT, 512,  512,  0);
    trw_k<<<dim3(16, 64), 256, 0, stream>>>(mlp1_w, wmlp1T, 512,  2048, 0);
    trw_k<<<dim3(64, 16), 256, 0, stream>>>(mlp2_w, wmlp2T, 2048, 512,  0);
    permx_k<<<NT * NC * NB, 64, 0, stream>>>(x, xT);

    for (int t = 0; t < NT; ++t) {
        gp.t = t;
        gemm_lif<0><<<dim3(98, 16), 256, 0, stream>>>(gp);  // q,k
        attn_k<<<dim3(25, NH), 256, 0, stream>>>(gp);       // attn LIF
        gemm_lif<1><<<dim3(98, 8), 256, 0, stream>>>(gp);   // proj -> v_y, xy
        gemm_lif<2><<<dim3(98, 32), 256, 0, stream>>>(gp);  // mlp1 -> h1_sp
        gemm_lif<3><<<dim3(98, 8), 256, 0, stream>>>(gp);   // mlp2 -> out
    }
}